// Round 3
// baseline (347.930 us; speedup 1.0000x reference)
//
#include <hip/hip_runtime.h>

// LIF spike scan: u_t = TAU*u_{t-1}*(1-o_{t-1}) + x_t; o_t = (u_t > VTH)
// x: [N_neurons=1048576][T=50] fp32, time contiguous. Output: spikes, same shape.
//
// Strategy: block = 256 threads = 256 neurons. Coalesced float2 global loads
// stage the [256][50] tile into LDS (row stride 51 -> odd stride, bank-conflict
// free per-thread row reads). Each thread walks its own neuron's 50 steps
// sequentially (recurrence), overwrites the LDS tile with spikes, then the
// block stores coalesced float2 back to global.
//
// Correctness: spikes are 0/1 and validated at 2e-2 absmax -> arithmetic must
// match numpy's separate mul/add (NO fma contraction), else a borderline
// u ~= 0.3 flips a spike and diverges the whole tail of that neuron.

constexpr int T = 50;
constexpr int ROWS = 256;      // neurons per block
constexpr int STRIDE = 51;     // padded LDS row stride (floats); odd -> conflict-free
constexpr float TAU = 0.3f;
constexpr float VTH = 0.3f;

__global__ __launch_bounds__(256) void lif_kernel(const float* __restrict__ x,
                                                  float* __restrict__ out) {
#pragma clang fp contract(off)
    __shared__ float tile[ROWS * STRIDE];  // 52,224 B -> 3 blocks/CU

    const int tid = threadIdx.x;
    const long long base = (long long)blockIdx.x * ROWS * T;
    const float2* xb = reinterpret_cast<const float2*>(x + base);
    float2* ob = reinterpret_cast<float2*>(out + base);

    constexpr int F2_PER_TILE = ROWS * T / 2;        // 6400 float2
    constexpr int ITERS = F2_PER_TILE / 256;         // 25 per thread
    constexpr int C2 = T / 2;                        // 25 float2 per row

    // ---- Load phase: fully coalesced (wave = 64 x 8B contiguous) ----
#pragma unroll
    for (int k = 0; k < ITERS; ++k) {
        int f2 = k * 256 + tid;
        float2 v = xb[f2];
        int row = f2 / C2;
        int c2 = f2 - row * C2;
        tile[row * STRIDE + c2 * 2]     = v.x;
        tile[row * STRIDE + c2 * 2 + 1] = v.y;
    }
    __syncthreads();

    // ---- Compute phase: one neuron per thread, sequential over T ----
    {
        float* myrow = &tile[tid * STRIDE];
        float u = 0.0f;
        float o = 0.0f;
#pragma unroll
        for (int t = 0; t < T; ++t) {
            float xt = myrow[t];
            float v = TAU * u;                      // separate mul (rounded)
            u = ((o != 0.0f) ? 0.0f : v) + xt;      // separate add; select blocks fma
            o = (u > VTH) ? 1.0f : 0.0f;
            myrow[t] = o;
        }
    }
    __syncthreads();

    // ---- Store phase: fully coalesced ----
#pragma unroll
    for (int k = 0; k < ITERS; ++k) {
        int f2 = k * 256 + tid;
        int row = f2 / C2;
        int c2 = f2 - row * C2;
        float2 v;
        v.x = tile[row * STRIDE + c2 * 2];
        v.y = tile[row * STRIDE + c2 * 2 + 1];
        ob[f2] = v;
    }
}

extern "C" void kernel_launch(void* const* d_in, const int* in_sizes, int n_in,
                              void* d_out, int out_size, void* d_ws, size_t ws_size,
                              hipStream_t stream) {
    const float* x = (const float*)d_in[0];
    // d_in[1] (ksi) is unused by the reference computation.
    float* out = (float*)d_out;

    const int n_neurons = in_sizes[0] / T;   // 1,048,576
    const int blocks = n_neurons / ROWS;     // 4096 (exact)

    lif_kernel<<<blocks, 256, 0, stream>>>(x, out);
}

// Round 5
// 344.781 us; speedup vs baseline: 1.0091x; 1.0091x over previous
//
#include <hip/hip_runtime.h>

// LIF spike scan: u_t = TAU*u_{t-1}*(1-o_{t-1}) + x_t; o_t = (u_t > VTH)
// x: [N=1048576 neurons][T=50] fp32, time contiguous. Out: 0/1 spikes, same shape.
//
// Round 4: flat LDS tile (stride 50) so global<->LDS staging is pure float4
// (ds_write_b128 / ds_read_b128, conflict-free), 12 x float4 + 1 x float2 per
// thread covers the 256x50 tile exactly. Compute phase walks each neuron's row
// in LDS (4-way bank conflict at stride 50 — negligible, compute ~4us total).
//
// Correctness: spikes validated at 2e-2 absmax; recurrence must match numpy's
// separate mul/add -> fp contract(off) + select-form update (no FMA).

constexpr int T = 50;
constexpr int ROWS = 256;          // neurons per block
constexpr float TAU = 0.3f;
constexpr float VTH = 0.3f;

__global__ __launch_bounds__(256) void lif_kernel(const float* __restrict__ x,
                                                  float* __restrict__ out) {
#pragma clang fp contract(off)
    __shared__ float tile[ROWS * T];   // 51,200 B -> 3 blocks/CU (12 waves)

    const int tid = threadIdx.x;
    const long long base = (long long)blockIdx.x * (ROWS * T);
    const float4* xb4 = reinterpret_cast<const float4*>(x + base);
    const float2* xb2 = reinterpret_cast<const float2*>(x + base);
    float4* ob4 = reinterpret_cast<float4*>(out + base);
    float2* ob2 = reinterpret_cast<float2*>(out + base);

    float4* t4 = reinterpret_cast<float4*>(tile);
    float2* t2 = reinterpret_cast<float2*>(tile);

    // ---- Load: 3200 float4 + 256 float2 per block, fully coalesced ----
#pragma unroll
    for (int k = 0; k < 12; ++k) {
        int i = k * 256 + tid;
        t4[i] = xb4[i];
    }
    t2[6144 + tid] = xb2[6144 + tid];   // tail: floats 12288..12799
    __syncthreads();

    // ---- Compute: one neuron per thread, sequential over T ----
    {
        float* myrow = &tile[tid * T];
        float u = 0.0f;
        float o = 0.0f;
#pragma unroll
        for (int t = 0; t < T; ++t) {
            float xt = myrow[t];
            float v = TAU * u;                    // separate mul (rounded)
            u = ((o != 0.0f) ? 0.0f : v) + xt;    // separate add; select blocks fma
            o = (u > VTH) ? 1.0f : 0.0f;
            myrow[t] = o;
        }
    }
    __syncthreads();

    // ---- Store: fully coalesced ----
#pragma unroll
    for (int k = 0; k < 12; ++k) {
        int i = k * 256 + tid;
        ob4[i] = t4[i];
    }
    ob2[6144 + tid] = t2[6144 + tid];
}

extern "C" void kernel_launch(void* const* d_in, const int* in_sizes, int n_in,
                              void* d_out, int out_size, void* d_ws, size_t ws_size,
                              hipStream_t stream) {
    const float* x = (const float*)d_in[0];
    // d_in[1] (ksi) is unused by the reference computation.
    float* out = (float*)d_out;

    const int n_neurons = in_sizes[0] / T;   // 1,048,576
    const int blocks = n_neurons / ROWS;     // 4096 (exact)

    lif_kernel<<<blocks, 256, 0, stream>>>(x, out);
}

// Round 8
// 333.378 us; speedup vs baseline: 1.0437x; 1.0342x over previous
//
#include <hip/hip_runtime.h>

// LIF spike scan: u_t = TAU*u_{t-1}*(1-o_{t-1}) + x_t; o_t = (u_t > VTH)
// x: [N=1048576 neurons][T=50] fp32, time contiguous. Out: 0/1 spikes, same shape.
//
// Round 8: Round-7 structure (ROWS=128, 6 blocks/CU, nontemporal streaming via
// clang ext_vector types) with the tail-index bug FIXED: tail float2 base is
// (12*ROWS*4)/2 = 3072, derived from constants instead of hand-copied.
//
// Correctness: spikes validated at 2e-2 absmax; recurrence must match numpy's
// separate mul/add -> fp contract(off) + select-form update (no FMA).

typedef float f32x4 __attribute__((ext_vector_type(4)));
typedef float f32x2 __attribute__((ext_vector_type(2)));

constexpr int T = 50;
constexpr int ROWS = 128;              // neurons per block
constexpr int F4_ITERS = 12;           // float4 staging iterations per thread
constexpr int F4_COUNT = F4_ITERS * ROWS;          // 1536 float4 = floats 0..6143
constexpr int TAIL_F2_BASE = F4_COUNT * 4 / 2;     // 3072: float2 idx of float 6144
constexpr float TAU = 0.3f;
constexpr float VTH = 0.3f;

static_assert(F4_COUNT * 4 + ROWS * 2 == ROWS * T, "tile coverage exact");

__global__ __launch_bounds__(128) void lif_kernel(const float* __restrict__ x,
                                                  float* __restrict__ out) {
#pragma clang fp contract(off)
    __shared__ float tile[ROWS * T];   // 25,600 B -> 6 blocks/CU (12 waves)

    const int tid = threadIdx.x;
    const long long base = (long long)blockIdx.x * (ROWS * T);
    const f32x4* xb4 = reinterpret_cast<const f32x4*>(x + base);
    const f32x2* xb2 = reinterpret_cast<const f32x2*>(x + base);
    f32x4* ob4 = reinterpret_cast<f32x4*>(out + base);
    f32x2* ob2 = reinterpret_cast<f32x2*>(out + base);

    f32x4* t4 = reinterpret_cast<f32x4*>(tile);
    f32x2* t2 = reinterpret_cast<f32x2*>(tile);

    // ---- Load: 1536 float4 + 128 float2 per block, fully coalesced, nt ----
#pragma unroll
    for (int k = 0; k < F4_ITERS; ++k) {
        int i = k * ROWS + tid;
        t4[i] = __builtin_nontemporal_load(&xb4[i]);
    }
    t2[TAIL_F2_BASE + tid] = __builtin_nontemporal_load(&xb2[TAIL_F2_BASE + tid]);
    __syncthreads();

    // ---- Compute: one neuron per thread, sequential over T ----
    {
        float* myrow = &tile[tid * T];
        float u = 0.0f;
        float o = 0.0f;
#pragma unroll
        for (int t = 0; t < T; ++t) {
            float xt = myrow[t];
            float v = TAU * u;                    // separate mul (rounded)
            u = ((o != 0.0f) ? 0.0f : v) + xt;    // separate add; select blocks fma
            o = (u > VTH) ? 1.0f : 0.0f;
            myrow[t] = o;
        }
    }
    __syncthreads();

    // ---- Store: fully coalesced, nt ----
#pragma unroll
    for (int k = 0; k < F4_ITERS; ++k) {
        int i = k * ROWS + tid;
        __builtin_nontemporal_store(t4[i], &ob4[i]);
    }
    __builtin_nontemporal_store(t2[TAIL_F2_BASE + tid], &ob2[TAIL_F2_BASE + tid]);
}

extern "C" void kernel_launch(void* const* d_in, const int* in_sizes, int n_in,
                              void* d_out, int out_size, void* d_ws, size_t ws_size,
                              hipStream_t stream) {
    const float* x = (const float*)d_in[0];
    // d_in[1] (ksi) is unused by the reference computation.
    float* out = (float*)d_out;

    const int n_neurons = in_sizes[0] / T;   // 1,048,576
    const int blocks = n_neurons / ROWS;     // 8192 (exact)

    lif_kernel<<<blocks, ROWS, 0, stream>>>(x, out);
}